// Round 7
// baseline (541.692 us; speedup 1.0000x reference)
//
#include <hip/hip_runtime.h>
#include <cstdint>
#include <cstddef>

#define NU 100000
#define NI 50000
#define NTOT 150000
#define EDIM 64
#define NE 1000000
#define NLAYERS 3
#define SCAN_CHUNK 1024
#define NBLK ((NTOT + SCAN_CHUNK - 1) / SCAN_CHUNK)   // 147
#define NTILES (NTOT / 16)                            // 9375
#define NPAIR (NTOT / 2)                              // 75000 (gather: 2 rows/wave)

// XCD-routed fill: 8 node-ranges (one per XCD), 4 edges/thread.
#define FILL_NRANGE 8
#define FILL_RSPAN (NTOT / FILL_NRANGE)               // 18750
#define FILL_EPT 4
#define FILL_EPB (256 * FILL_EPT)                     // 1024 edges/block
#define FILL_NCHUNK ((NE + FILL_EPB - 1) / FILL_EPB)  // 977

// byte-packed degree histogram: 4 nodes/word, 32768 nodes per 32KB block.
#define HB_BYTES 32768
#define HB_WORDS (HB_BYTES / 4)
#define NSLICE 128
#define ESLICE ((NE + NSLICE - 1) / NSLICE)           // 7813
#define NRANGE_U 4
#define NRANGE_I 2
#define NRANGE (NRANGE_U + NRANGE_I)
#define NWORDS (NTOT / 4)                             // 37500

typedef __attribute__((ext_vector_type(8))) short short8;   // 8 bf16 (4 VGPRs)
typedef __attribute__((ext_vector_type(4))) float floatx4;  // 4 fp32 acc

// ---------------- bf16 helpers (raw-bit, RNE) ----------------
__device__ inline unsigned short f2bf(float f) {
    unsigned u = __float_as_uint(f);
    u += 0x7fffu + ((u >> 16) & 1u);
    return (unsigned short)(u >> 16);
}
__device__ inline unsigned pack_bf2(float a, float b) {
    unsigned ua = __float_as_uint(a); ua += 0x7fffu + ((ua >> 16) & 1u);
    unsigned ub = __float_as_uint(b); ub += 0x7fffu + ((ub >> 16) & 1u);
    return (ua >> 16) | (ub & 0xffff0000u);
}
__device__ inline float bf_lo(unsigned u) { return __uint_as_float(u << 16); }
__device__ inline float bf_hi(unsigned u) { return __uint_as_float(u & 0xffff0000u); }

// ---------------- degree histogram, byte-packed LDS ----------------
__global__ __launch_bounds__(256) void k_hist(const int* __restrict__ eu,
                                              const int* __restrict__ ei,
                                              unsigned* __restrict__ partial) {
    __shared__ unsigned h[HB_WORDS];
    int r = blockIdx.x / NSLICE;
    int s = blockIdx.x % NSLICE;
    const int* arr;
    int base, gbyte, lim;
    if (r < NRANGE_U) {
        arr = eu; base = r * HB_BYTES; gbyte = base;
        lim = min(HB_BYTES, NU - base);
    } else {
        arr = ei; base = (r - NRANGE_U) * HB_BYTES; gbyte = NU + base;
        lim = min(HB_BYTES, NI - base);
    }
    for (int i = threadIdx.x; i < HB_WORDS; i += 256) h[i] = 0;
    __syncthreads();
    const int e0 = s * ESLICE, e1 = min(NE, e0 + ESLICE);
    for (int e = e0 + threadIdx.x; e < e1; e += 256) {
        unsigned local = (unsigned)(arr[e] - base);
        if (local < (unsigned)HB_BYTES)
            atomicAdd(&h[local >> 2], 1u << ((local & 3u) * 8u));
    }
    __syncthreads();
    unsigned* dst = partial + (size_t)s * NWORDS + (gbyte >> 2);
    int lw = lim >> 2;
    for (int i = threadIdx.x; i < lw; i += 256) dst[i] = h[i];
}

__global__ void k_merge(const unsigned* __restrict__ partial, int* __restrict__ deg,
                        float* __restrict__ isq, float* __restrict__ inv) {
    int n = blockIdx.x * blockDim.x + threadIdx.x;
    if (n >= NWORDS) return;
    unsigned se = 0, so = 0;
    for (int s = 0; s < NSLICE; ++s) {
        unsigned v = partial[(size_t)s * NWORDS + n];
        se += v & 0x00ff00ffu;
        so += (v >> 8) & 0x00ff00ffu;
    }
    int d[4];
    d[0] = se & 0xffff; d[1] = so & 0xffff;
    d[2] = se >> 16;    d[3] = so >> 16;
    ((int4*)deg)[n] = make_int4(d[0], d[1], d[2], d[3]);
    float4 q, iv;
    float* qp = &q.x; float* ip = &iv.x;
#pragma unroll
    for (int j = 0; j < 4; ++j) {
        float df = (float)d[j];
        qp[j] = d[j] > 0 ? 1.0f / sqrtf(df) : 0.f;
        ip[j] = d[j] > 0 ? 1.0f / df : 0.f;
    }
    ((float4*)isq)[n] = q;
    ((float4*)inv)[n] = iv;
}

// ---------------- scan kernels ----------------

__global__ void k_blocksum(const int* __restrict__ deg, int* __restrict__ partials) {
    __shared__ int sm[256];
    int b = blockIdx.x, t = threadIdx.x;
    int base = b * SCAN_CHUNK + t * 4;
    int s = 0;
#pragma unroll
    for (int j = 0; j < 4; ++j) {
        int idx = base + j;
        if (idx < NTOT) s += deg[idx];
    }
    sm[t] = s;
    __syncthreads();
    for (int off = 128; off > 0; off >>= 1) {
        if (t < off) sm[t] += sm[t + off];
        __syncthreads();
    }
    if (t == 0) partials[b] = sm[0];
}

__global__ void k_scanpartials(int* __restrict__ partials, int nblk) {
    __shared__ int sm[256];
    int t = threadIdx.x;
    int v = (t < nblk) ? partials[t] : 0;
    sm[t] = v;
    __syncthreads();
    for (int off = 1; off < 256; off <<= 1) {
        int tmp = (t >= off) ? sm[t - off] : 0;
        __syncthreads();
        sm[t] += tmp;
        __syncthreads();
    }
    if (t < nblk) partials[t] = sm[t] - v;   // exclusive
}

__global__ void k_scanfinal(const int* __restrict__ deg, const int* __restrict__ partials,
                            int* __restrict__ start, int* __restrict__ cursor) {
    __shared__ int sm[256];
    int b = blockIdx.x, t = threadIdx.x;
    int base = b * SCAN_CHUNK + t * 4;
    int v[4];
    int s = 0;
#pragma unroll
    for (int j = 0; j < 4; ++j) {
        int idx = base + j;
        v[j] = (idx < NTOT) ? deg[idx] : 0;
        s += v[j];
    }
    sm[t] = s;
    __syncthreads();
    for (int off = 1; off < 256; off <<= 1) {
        int tmp = (t >= off) ? sm[t - off] : 0;
        __syncthreads();
        sm[t] += tmp;
        __syncthreads();
    }
    int excl = partials[b] + sm[t] - s;
#pragma unroll
    for (int j = 0; j < 4; ++j) {
        int idx = base + j;
        if (idx < NTOT) {
            start[idx] = excl;
            cursor[idx] = excl;
            excl += v[j];
        }
    }
}

// XCD-routed CSR fill, single launch, 4 edges/thread, PHASE-SPLIT atomics.
// Phase 1 issues all 8 (edge,endpoint) atomicAdds back-to-back with no
// dependent use between them -> 8 returns outstanding concurrently. Phase 2
// does the predicated stores; the first store's waitcnt covers (nearly) all
// atomics at once. Round-6 counters showed the old per-branch atomic->wait->
// store layout serialized the chains within the wave (fill stuck at 87us
// regardless of chains/thread).
__global__ __launch_bounds__(256) void k_fill_xcd(const int* __restrict__ eu,
                                                  const int* __restrict__ ei,
                                                  int* __restrict__ cursor,
                                                  int* __restrict__ csr) {
    int range = blockIdx.x & (FILL_NRANGE - 1);
    int ebase = (blockIdx.x >> 3) * FILL_EPB + threadIdx.x;
    int lo = range * FILL_RSPAN;
    int hi = lo + FILL_RSPAN;
    int u[FILL_EPT], v[FILL_EPT];
#pragma unroll
    for (int k = 0; k < FILL_EPT; ++k) {
        int e = ebase + k * 256;
        u[k] = (e < NE) ? eu[e] : -1;
        v[k] = (e < NE) ? NU + ei[e] : -1;
    }
    int pu[FILL_EPT], pv[FILL_EPT];
    // phase 1: issue every atomic; results land in VGPRs, no dependent use yet
#pragma unroll
    for (int k = 0; k < FILL_EPT; ++k) {
        pu[k] = (u[k] >= lo && u[k] < hi) ? atomicAdd(&cursor[u[k]], 1) : -1;
        pv[k] = (v[k] >= lo && v[k] < hi) ? atomicAdd(&cursor[v[k]], 1) : -1;
    }
    // phase 2: stores (one waitcnt drains nearly all outstanding atomics)
#pragma unroll
    for (int k = 0; k < FILL_EPT; ++k) {
        if (pu[k] >= 0) csr[pu[k]] = v[k];
        if (pv[k] >= 0) csr[pv[k]] = u[k];
    }
}

// init (fused): snap0 = bf16(concat(u,i)); embS = bf16(isq*emb) into gbuf;
// + W f32->bf16 pre-conversion (first 3072 threads);
// + zero the sentinel row NTOT of Ebuf and gbuf (first 16 threads).
__global__ void k_init(const float* __restrict__ ue, const float* __restrict__ ie,
                       const float* __restrict__ isq,
                       unsigned* __restrict__ snap0, unsigned* gbuf,
                       const float* __restrict__ Wg, const float* __restrict__ Wb,
                       unsigned short* __restrict__ wgb, unsigned short* __restrict__ wbb,
                       unsigned* __restrict__ Ebuf) {
    int i = blockIdx.x * blockDim.x + threadIdx.x;
    const int n4 = NTOT * EDIM / 4;
    const int nw4 = NLAYERS * 4096 / 4;   // 3072
    if (i < nw4) {
        float4 g4 = ((const float4*)Wg)[i];
        float4 b4 = ((const float4*)Wb)[i];
        uint2 g, b;
        g.x = pack_bf2(g4.x, g4.y); g.y = pack_bf2(g4.z, g4.w);
        b.x = pack_bf2(b4.x, b4.y); b.y = pack_bf2(b4.z, b4.w);
        ((uint2*)wgb)[i] = g;
        ((uint2*)wbb)[i] = b;
    }
    if (i < 16) {
        ((uint2*)(Ebuf + NTOT * 32))[i] = make_uint2(0u, 0u);
        ((uint2*)(gbuf + NTOT * 32))[i] = make_uint2(0u, 0u);
    }
    if (i < n4) {
        const int nu4 = NU * EDIM / 4;
        float4 v = (i < nu4) ? ((const float4*)ue)[i] : ((const float4*)ie)[i - nu4];
        float s = isq[i >> 4];
        uint2 b, bs;
        b.x = pack_bf2(v.x, v.y);
        b.y = pack_bf2(v.z, v.w);
        bs.x = pack_bf2(v.x * s, v.y * s);
        bs.y = pack_bf2(v.z * s, v.w * s);
        ((uint2*)snap0)[i] = b;
        ((uint2*)gbuf)[i] = bs;
    }
}

// ---------------- sparse gather (pull), bf16 rows, unweighted ----------------
// v4: TWO rows per wave — lanes 0-31 own row 2gw, lanes 32-63 own row 2gw+1.
// Each half broadcasts its own neighbor list via per-lane-src shfl; every lane
// accumulates ALL neighbors of its row (dword l2), so no cross-lane reduce.
// 16 independent loads in flight per wave. Out-of-range slots read the zero
// sentinel row at index NTOT.
__global__ __launch_bounds__(256) void k_gather(
    const unsigned* __restrict__ in_bf, unsigned* __restrict__ out_bf,
    const int* __restrict__ csr, const int* __restrict__ start,
    const int* __restrict__ deg, const float* __restrict__ sA) {
    int gw = (blockIdx.x * 256 + threadIdx.x) >> 6;   // wave id = row pair
    int lane = threadIdx.x & 63;
    if (gw >= NPAIR) return;
    int l2 = lane & 31;
    int hbase = lane & 32;                 // 0 or 32: this half's lane base
    int row = gw * 2 + (lane >> 5);
    int s0 = start[row];
    int dg = deg[row];
    int dgo = __shfl_xor(dg, 32);          // other half's degree
    int dgmax = max(dg, dgo);              // uniform across the wave
    float acc0 = 0.f, acc1 = 0.f;
    for (int j0 = 0; j0 < dgmax; j0 += 32) {
        int nidx = NTOT;                   // sentinel zero row
        if (j0 + l2 < dg) nidx = csr[s0 + j0 + l2];
        int jlim = min(32, dgmax - j0);
        for (int j = 0; j < jlim; j += 16) {
            int mm[16];
            unsigned uu[16];
#pragma unroll
            for (int k = 0; k < 16; ++k)
                mm[k] = __shfl(nidx, hbase + j + k);
#pragma unroll
            for (int k = 0; k < 16; ++k)
                uu[k] = in_bf[mm[k] * 32 + l2];
#pragma unroll
            for (int k = 0; k < 16; ++k) {
                acc0 += bf_lo(uu[k]);
                acc1 += bf_hi(uu[k]);
            }
        }
    }
    float s = sA[row];
    out_bf[row * 32 + l2] = pack_bf2(s * acc0, s * acc1);
}

// ---------------- dense per-row update via MFMA (all-bf16 state) ----------------
// One wave per 16-row tile. Reads g rows (from gbuf) + a rows (snap_prev).
// writeScaled: also write embS = isq*emb bf16 IN PLACE over gbuf (per-tile
// local; tiles disjoint across waves). finalOut: instead of writing snap_l,
// fuse the output mean: out = 0.25*(emb_f32 + snap1 + a_prev + rr) where
// rr is this layer's (unrounded) normalized embedding. gbuf intentionally
// NOT __restrict__.
__global__ __launch_bounds__(256) void k_dense_mfma(
    const unsigned short* __restrict__ a_prev, unsigned* gbuf,
    unsigned short* __restrict__ snap_l, const float* __restrict__ isq,
    const unsigned short* __restrict__ wgb, const unsigned short* __restrict__ wbb,
    const float* __restrict__ bg, const float* __restrict__ bb, int writeScaled,
    int finalOut, const unsigned short* __restrict__ s1,
    const float* __restrict__ ue, const float* __restrict__ ie,
    float* __restrict__ outp) {
    int lane = threadIdx.x & 63;
    int lanelo = lane & 15;
    int quad = lane >> 4;
    int wid = (blockIdx.x * blockDim.x + threadIdx.x) >> 6;
    if (wid >= NTILES) return;

    // B-fragments from pre-converted bf16 W (vector loads, no conversion)
    short8 bWg[4][2], bWb[4][2];
#pragma unroll
    for (int t = 0; t < 4; ++t) {
#pragma unroll
        for (int h = 0; h < 2; ++h) {
            int n = t * 16 + lanelo;
            int k0 = h * 32 + quad * 8;
            bWg[t][h] = *(const short8*)&wgb[n * 64 + k0];
            bWb[t][h] = *(const short8*)&wbb[n * 64 + k0];
        }
    }
    float bgv[4], bbv[4];
#pragma unroll
    for (int t = 0; t < 4; ++t) {
        bgv[t] = bg[t * 16 + lanelo];
        bbv[t] = bb[t * 16 + lanelo];
    }

    int rbase = wid * 16;
    int arow = rbase + lanelo;
    short8 aG[2], aAG[2];
#pragma unroll
    for (int h = 0; h < 2; ++h) {
        uint4 ug = *(const uint4*)(gbuf + arow * 32 + h * 16 + quad * 4);
        uint4 ua = *(const uint4*)((const unsigned*)a_prev + arow * 32 + h * 16 + quad * 4);
        aG[h] = *(const short8*)&ug;
        uint4 up;
        up.x = pack_bf2(bf_lo(ua.x) * bf_lo(ug.x), bf_hi(ua.x) * bf_hi(ug.x));
        up.y = pack_bf2(bf_lo(ua.y) * bf_lo(ug.y), bf_hi(ua.y) * bf_hi(ug.y));
        up.z = pack_bf2(bf_lo(ua.z) * bf_lo(ug.z), bf_hi(ua.z) * bf_hi(ug.z));
        up.w = pack_bf2(bf_lo(ua.w) * bf_lo(ug.w), bf_hi(ua.w) * bf_hi(ug.w));
        aAG[h] = *(const short8*)&up;
    }
    floatx4 accg[4], accb[4];
#pragma unroll
    for (int t = 0; t < 4; ++t) {
        accg[t] = (floatx4)(0.f);
        accb[t] = (floatx4)(0.f);
    }
#pragma unroll
    for (int t = 0; t < 4; ++t) {
#pragma unroll
        for (int h = 0; h < 2; ++h) {
            accg[t] = __builtin_amdgcn_mfma_f32_16x16x32_bf16(aG[h], bWg[t][h], accg[t], 0, 0, 0);
            accb[t] = __builtin_amdgcn_mfma_f32_16x16x32_bf16(aAG[h], bWb[t][h], accb[t], 0, 0, 0);
        }
    }
    // epilogue in C/D layout: row = rbase + quad*4 + i, col = t*16 + lanelo
    float nv[4][4];
    float ss[4] = {0.f, 0.f, 0.f, 0.f};
#pragma unroll
    for (int i = 0; i < 4; ++i) {
        int r = rbase + quad * 4 + i;
#pragma unroll
        for (int t = 0; t < 4; ++t) {
            float a = __uint_as_float((unsigned)a_prev[r * 64 + t * 16 + lanelo] << 16);
            float e1 = accg[t][i] + bgv[t] + a;
            e1 = e1 >= 0.f ? e1 : 0.2f * e1;
            float e2 = accb[t][i] + bbv[t];
            e2 = e2 >= 0.f ? e2 : 0.2f * e2;
            float v = e1 + e2;
            nv[i][t] = v;
            ss[i] += v * v;
        }
    }
#pragma unroll
    for (int m = 1; m < 16; m <<= 1) {
#pragma unroll
        for (int i = 0; i < 4; ++i) ss[i] += __shfl_xor(ss[i], m, 64);
    }
#pragma unroll
    for (int i = 0; i < 4; ++i) {
        int r = rbase + quad * 4 + i;
        float rn = 1.0f / fmaxf(sqrtf(ss[i]), 1e-12f);
        float sc = isq[r] * rn;
        if (finalOut) {
#pragma unroll
            for (int t = 0; t < 4; ++t) {
                int idx = r * 64 + t * 16 + lanelo;
                float rr = nv[i][t] * rn;
                float s1v = __uint_as_float((unsigned)s1[idx] << 16);
                float s2v = __uint_as_float((unsigned)a_prev[idx] << 16);
                float ev = (r < NU) ? ue[idx] : ie[idx - NU * 64];
                outp[idx] = 0.25f * (ev + s1v + s2v + rr);
            }
        } else {
#pragma unroll
            for (int t = 0; t < 4; ++t) {
                int idx = r * 64 + t * 16 + lanelo;
                float rr = nv[i][t] * rn;
                snap_l[idx] = f2bf(rr);
                if (writeScaled)
                    ((unsigned short*)gbuf)[idx] = f2bf(nv[i][t] * sc);
            }
        }
    }
}

// ---------------- launch ----------------

extern "C" void kernel_launch(void* const* d_in, const int* in_sizes, int n_in,
                              void* d_out, int out_size, void* d_ws, size_t ws_size,
                              hipStream_t stream) {
    const float* u_emb = (const float*)d_in[0];
    const float* i_emb = (const float*)d_in[1];
    const float* Wgc = (const float*)d_in[2];
    const float* bgc = (const float*)d_in[3];
    const float* Wbi = (const float*)d_in[4];
    const float* bbi = (const float*)d_in[5];
    const int* edge_u = (const int*)d_in[6];
    const int* edge_i = (const int*)d_in[7];
    float* out = (float*)d_out;

    char* w = (char*)d_ws;
    auto alloc = [&](size_t bytes) {
        char* p = w;
        w += (bytes + 255) & ~(size_t)255;
        return p;
    };
    const size_t ROWBYTES = (size_t)(NTOT + 1) * EDIM * 2;   // +1 sentinel row
    int* deg = (int*)alloc((size_t)NTOT * 4);
    int* start = (int*)alloc((size_t)NTOT * 4);
    int* cursor = (int*)alloc((size_t)NTOT * 4);
    int* partials = (int*)alloc(256 * 4);
    int* csr = (int*)alloc((size_t)2 * NE * 4);
    float* isq = (float*)alloc((size_t)NTOT * 4);
    float* inv = (float*)alloc((size_t)NTOT * 4);
    unsigned short* wgb = (unsigned short*)alloc((size_t)NLAYERS * 4096 * 2);
    unsigned short* wbb = (unsigned short*)alloc((size_t)NLAYERS * 4096 * 2);
    unsigned* snap0 = (unsigned*)alloc((size_t)NTOT * EDIM * 2);
    unsigned* snap1 = (unsigned*)alloc((size_t)NTOT * EDIM * 2);
    unsigned* snap2 = (unsigned*)alloc((size_t)NTOT * EDIM * 2);
    unsigned* Ebuf = (unsigned*)alloc(ROWBYTES);    // = hpartial
    unsigned* gbuf = (unsigned*)alloc(ROWBYTES);    // = embS (in-place)
    unsigned* hpartial = Ebuf;                      // 19.2 MB fits; dead pre-init

    // graph prep
    k_hist<<<NRANGE * NSLICE, 256, 0, stream>>>(edge_u, edge_i, hpartial);
    k_merge<<<(NWORDS + 255) / 256, 256, 0, stream>>>(hpartial, deg, isq, inv);
    k_blocksum<<<NBLK, 256, 0, stream>>>(deg, partials);
    k_scanpartials<<<1, 256, 0, stream>>>(partials, NBLK);
    k_scanfinal<<<NBLK, 256, 0, stream>>>(deg, partials, start, cursor);
    k_fill_xcd<<<FILL_NCHUNK * FILL_NRANGE, 256, 0, stream>>>(edge_u, edge_i, cursor, csr);
    k_init<<<(NTOT * EDIM / 4 + 255) / 256, 256, 0, stream>>>(
        u_emb, i_emb, isq, snap0, gbuf, Wgc, Wbi, wgb, wbb, Ebuf);

    const int gatherBlocks = (NPAIR * 64 + 255) / 256;  // one wave per 2 rows
    const int denseBlocks = (NTILES * 64 + 255) / 256;  // one wave per 16-row tile
    const unsigned short* aprev[3] = {(unsigned short*)snap0, (unsigned short*)snap1,
                                      (unsigned short*)snap2};
    unsigned short* snaps[3] = {(unsigned short*)snap1, (unsigned short*)snap2,
                                (unsigned short*)snap1 /*unused for l=2*/};
    for (int l = 0; l < NLAYERS; ++l) {
        // E[n] = inv[n] * sum embS[m]      (embS = isq*emb, pre-scaled)
        k_gather<<<gatherBlocks, 256, 0, stream>>>(gbuf, Ebuf, csr, start, deg, inv);
        // g[n] = isq[n] * sum E[m]
        k_gather<<<gatherBlocks, 256, 0, stream>>>(Ebuf, gbuf, csr, start, deg, isq);
        k_dense_mfma<<<denseBlocks, 256, 0, stream>>>(
            aprev[l], gbuf, snaps[l], isq, wgb + (size_t)l * 4096, wbb + (size_t)l * 4096,
            bgc + (size_t)l * 64, bbi + (size_t)l * 64,
            l < NLAYERS - 1 ? 1 : 0,              // writeScaled
            l == NLAYERS - 1 ? 1 : 0,             // finalOut (fused k_out)
            (const unsigned short*)snap1, u_emb, i_emb, out);
    }
}

// Round 8
// 535.916 us; speedup vs baseline: 1.0108x; 1.0108x over previous
//
#include <hip/hip_runtime.h>
#include <cstdint>
#include <cstddef>

#define NU 100000
#define NI 50000
#define NTOT 150000
#define EDIM 64
#define NE 1000000
#define NLAYERS 3
#define NTILES (NTOT / 16)                            // 9375
#define NPAIR (NTOT / 2)                              // 75000 (gather: 2 rows/wave)

// ---- binned CSR build ----
#define NBKT 256
#define NPB 586                    // nodes per bucket (256*586 = 150016 >= NTOT)
#define NSHARD 8                   // shard = blockIdx&7 -> XCD-local tails
#define BCAP 1920                  // pairs per (bucket,shard); mean 1465, +10 sigma
#define BCUR_STRIDE 16             // u32s -> 64B per cursor (no same-line atomics)
#define BIN_EPB 1024               // edges per binpairs block
#define BIN_NBLK ((NE + BIN_EPB - 1) / BIN_EPB)       // 977
#define SLICE_CAP 13312            // ints; max bucket pair-count ~12.1K

typedef __attribute__((ext_vector_type(8))) short short8;   // 8 bf16 (4 VGPRs)
typedef __attribute__((ext_vector_type(4))) float floatx4;  // 4 fp32 acc

// ---------------- bf16 helpers (raw-bit, RNE) ----------------
__device__ inline unsigned short f2bf(float f) {
    unsigned u = __float_as_uint(f);
    u += 0x7fffu + ((u >> 16) & 1u);
    return (unsigned short)(u >> 16);
}
__device__ inline unsigned pack_bf2(float a, float b) {
    unsigned ua = __float_as_uint(a); ua += 0x7fffu + ((ua >> 16) & 1u);
    unsigned ub = __float_as_uint(b); ub += 0x7fffu + ((ub >> 16) & 1u);
    return (ua >> 16) | (ub & 0xffff0000u);
}
__device__ inline float bf_lo(unsigned u) { return __uint_as_float(u << 16); }
__device__ inline float bf_hi(unsigned u) { return __uint_as_float(u & 0xffff0000u); }

// ---------------- phase A: bin (node, other) pairs by node range ----------------
// Each (edge,endpoint) is appended to bucket node/NPB, shard blockIdx&7.
// Tail-append stores are line-dense and (with shard==XCD) single-L2-resident,
// unlike the old cursor-scatter fill whose 4B stores dirtied each csr line
// ~12 separate times (WRITE_SIZE 95MB for 8MB useful, rounds 4-7).
__global__ __launch_bounds__(256) void k_binpairs(const int* __restrict__ eu,
                                                  const int* __restrict__ ei,
                                                  unsigned* __restrict__ bcur,
                                                  uint2* __restrict__ bbuf) {
    int shard = blockIdx.x & (NSHARD - 1);
    int ebase = blockIdx.x * BIN_EPB + threadIdx.x;
    int n_[8], o_[8];
#pragma unroll
    for (int k = 0; k < 4; ++k) {
        int e = ebase + k * 256;
        int u = (e < NE) ? eu[e] : -1;
        int v = (e < NE) ? NU + ei[e] : -1;
        n_[k] = u;     o_[k] = v;
        n_[k + 4] = v; o_[k + 4] = u;
    }
    int bb_[8];
#pragma unroll
    for (int k = 0; k < 8; ++k) bb_[k] = (n_[k] >= 0) ? (n_[k] / NPB) : -1;
    int pp_[8];
#pragma unroll
    for (int k = 0; k < 8; ++k)
        pp_[k] = (bb_[k] >= 0)
                     ? (int)atomicAdd(&bcur[(bb_[k] * NSHARD + shard) * BCUR_STRIDE], 1u)
                     : -1;
#pragma unroll
    for (int k = 0; k < 8; ++k)
        if (pp_[k] >= 0 && pp_[k] < BCAP)
            bbuf[(size_t)(bb_[k] * NSHARD + shard) * BCAP + pp_[k]] =
                make_uint2((unsigned)n_[k], (unsigned)o_[k]);
}

// ---------------- bucket-total exclusive prefix (1 block) ----------------
__global__ void k_bktprefix(const unsigned* __restrict__ bcur, int* __restrict__ bktbase) {
    __shared__ int sm[256];
    int t = threadIdx.x;   // t = bucket
    int tot = 0;
    for (int s = 0; s < NSHARD; ++s) tot += (int)bcur[(t * NSHARD + s) * BCUR_STRIDE];
    sm[t] = tot;
    __syncthreads();
    for (int off = 1; off < 256; off <<= 1) {
        int tmp = (t >= off) ? sm[t - off] : 0;
        __syncthreads();
        sm[t] += tmp;
        __syncthreads();
    }
    bktbase[t] = sm[t] - tot;   // exclusive
}

// ---------------- phase B: per-bucket degree/scan/CSR build, coalesced flush ----
// One block per bucket. Produces deg/start/isq/inv with values IDENTICAL to the
// old hist+merge+scan pipeline (bucket-major prefix == node-order prefix since
// buckets are contiguous node ranges). CSR slice assembled in LDS, flushed with
// fully coalesced stores.
__global__ __launch_bounds__(1024) void k_buildcsr(
    const uint2* __restrict__ bbuf, const unsigned* __restrict__ bcur,
    const int* __restrict__ bktbase, int* __restrict__ deg, int* __restrict__ start,
    float* __restrict__ isq, float* __restrict__ inv, int* __restrict__ csr) {
    __shared__ int slice[SLICE_CAP];   // scan temp (first 1024), then csr slice
    __shared__ int lcur[NPB];          // per-node count, then placement cursor
    __shared__ int scnt[NSHARD];
    int b = blockIdx.x;
    int t = threadIdx.x;
    int n0 = b * NPB;
    int nn = NTOT - n0;
    if (nn > NPB) nn = NPB;
    if (nn < 0) nn = 0;
    if (t < NPB) lcur[t] = 0;
    if (t < NSHARD) {
        int c = (int)bcur[(b * NSHARD + t) * BCUR_STRIDE];
        scnt[t] = c < BCAP ? c : BCAP;
    }
    __syncthreads();
    // count pass
    for (int s = 0; s < NSHARD; ++s) {
        int c = scnt[s];
        const uint2* pb = bbuf + (size_t)(b * NSHARD + s) * BCAP;
        for (int i = t; i < c; i += 1024) atomicAdd(&lcur[(int)pb[i].x - n0], 1);
    }
    __syncthreads();
    // exclusive scan over nn counts (1024-wide Hillis-Steele in slice[])
    int cnt_t = (t < nn) ? lcur[t] : 0;
    slice[t] = cnt_t;
    __syncthreads();
    for (int off = 1; off < 1024; off <<= 1) {
        int tmp = (t >= off) ? slice[t - off] : 0;
        __syncthreads();
        slice[t] += tmp;
        __syncthreads();
    }
    int excl = slice[t] - cnt_t;
    int slen = slice[1023];            // total pairs in bucket
    int bb = bktbase[b];
    if (t < nn) {
        int n = n0 + t;
        deg[n] = cnt_t;
        start[n] = bb + excl;
        float df = (float)cnt_t;
        isq[n] = cnt_t > 0 ? 1.0f / sqrtf(df) : 0.f;
        inv[n] = cnt_t > 0 ? 1.0f / df : 0.f;
    }
    __syncthreads();                   // everyone done reading slice & lcur
    if (t < nn) lcur[t] = excl;        // reuse as placement cursor
    __syncthreads();
    // place pass
    for (int s = 0; s < NSHARD; ++s) {
        int c = scnt[s];
        const uint2* pb = bbuf + (size_t)(b * NSHARD + s) * BCAP;
        for (int i = t; i < c; i += 1024) {
            uint2 pr = pb[i];
            int idx = atomicAdd(&lcur[(int)pr.x - n0], 1);
            if (idx < SLICE_CAP) slice[idx] = (int)pr.y;
        }
    }
    __syncthreads();
    if (slen > SLICE_CAP) slen = SLICE_CAP;
    for (int i = t; i < slen; i += 1024) csr[bb + i] = slice[i];
}

// init (fused): snap0 = bf16(concat(u,i)); embS = bf16(isq*emb) into gbuf;
// + W f32->bf16 pre-conversion (first 3072 threads);
// + zero the sentinel row NTOT of Ebuf and gbuf (first 16 threads).
__global__ void k_init(const float* __restrict__ ue, const float* __restrict__ ie,
                       const float* __restrict__ isq,
                       unsigned* __restrict__ snap0, unsigned* gbuf,
                       const float* __restrict__ Wg, const float* __restrict__ Wb,
                       unsigned short* __restrict__ wgb, unsigned short* __restrict__ wbb,
                       unsigned* __restrict__ Ebuf) {
    int i = blockIdx.x * blockDim.x + threadIdx.x;
    const int n4 = NTOT * EDIM / 4;
    const int nw4 = NLAYERS * 4096 / 4;   // 3072
    if (i < nw4) {
        float4 g4 = ((const float4*)Wg)[i];
        float4 b4 = ((const float4*)Wb)[i];
        uint2 g, b;
        g.x = pack_bf2(g4.x, g4.y); g.y = pack_bf2(g4.z, g4.w);
        b.x = pack_bf2(b4.x, b4.y); b.y = pack_bf2(b4.z, b4.w);
        ((uint2*)wgb)[i] = g;
        ((uint2*)wbb)[i] = b;
    }
    if (i < 16) {
        ((uint2*)(Ebuf + NTOT * 32))[i] = make_uint2(0u, 0u);
        ((uint2*)(gbuf + NTOT * 32))[i] = make_uint2(0u, 0u);
    }
    if (i < n4) {
        const int nu4 = NU * EDIM / 4;
        float4 v = (i < nu4) ? ((const float4*)ue)[i] : ((const float4*)ie)[i - nu4];
        float s = isq[i >> 4];
        uint2 b, bs;
        b.x = pack_bf2(v.x, v.y);
        b.y = pack_bf2(v.z, v.w);
        bs.x = pack_bf2(v.x * s, v.y * s);
        bs.y = pack_bf2(v.z * s, v.w * s);
        ((uint2*)snap0)[i] = b;
        ((uint2*)gbuf)[i] = bs;
    }
}

// ---------------- sparse gather (pull), bf16 rows, unweighted ----------------
// v4: TWO rows per wave — lanes 0-31 own row 2gw, lanes 32-63 own row 2gw+1.
// Each half broadcasts its own neighbor list via per-lane-src shfl; every lane
// accumulates ALL neighbors of its row (dword l2), so no cross-lane reduce.
// 16 independent loads in flight per wave. Out-of-range slots read the zero
// sentinel row at index NTOT.
__global__ __launch_bounds__(256) void k_gather(
    const unsigned* __restrict__ in_bf, unsigned* __restrict__ out_bf,
    const int* __restrict__ csr, const int* __restrict__ start,
    const int* __restrict__ deg, const float* __restrict__ sA) {
    int gw = (blockIdx.x * 256 + threadIdx.x) >> 6;   // wave id = row pair
    int lane = threadIdx.x & 63;
    if (gw >= NPAIR) return;
    int l2 = lane & 31;
    int hbase = lane & 32;                 // 0 or 32: this half's lane base
    int row = gw * 2 + (lane >> 5);
    int s0 = start[row];
    int dg = deg[row];
    int dgo = __shfl_xor(dg, 32);          // other half's degree
    int dgmax = max(dg, dgo);              // uniform across the wave
    float acc0 = 0.f, acc1 = 0.f;
    for (int j0 = 0; j0 < dgmax; j0 += 32) {
        int nidx = NTOT;                   // sentinel zero row
        if (j0 + l2 < dg) nidx = csr[s0 + j0 + l2];
        int jlim = min(32, dgmax - j0);
        for (int j = 0; j < jlim; j += 16) {
            int mm[16];
            unsigned uu[16];
#pragma unroll
            for (int k = 0; k < 16; ++k)
                mm[k] = __shfl(nidx, hbase + j + k);
#pragma unroll
            for (int k = 0; k < 16; ++k)
                uu[k] = in_bf[mm[k] * 32 + l2];
#pragma unroll
            for (int k = 0; k < 16; ++k) {
                acc0 += bf_lo(uu[k]);
                acc1 += bf_hi(uu[k]);
            }
        }
    }
    float s = sA[row];
    out_bf[row * 32 + l2] = pack_bf2(s * acc0, s * acc1);
}

// ---------------- dense per-row update via MFMA (all-bf16 state) ----------------
// One wave per 16-row tile. Reads g rows (from gbuf) + a rows (snap_prev).
// writeScaled: also write embS = isq*emb bf16 IN PLACE over gbuf (per-tile
// local; tiles disjoint across waves). finalOut: instead of writing snap_l,
// fuse the output mean: out = 0.25*(emb_f32 + snap1 + a_prev + rr) where
// rr is this layer's (unrounded) normalized embedding. gbuf intentionally
// NOT __restrict__.
__global__ __launch_bounds__(256) void k_dense_mfma(
    const unsigned short* __restrict__ a_prev, unsigned* gbuf,
    unsigned short* __restrict__ snap_l, const float* __restrict__ isq,
    const unsigned short* __restrict__ wgb, const unsigned short* __restrict__ wbb,
    const float* __restrict__ bg, const float* __restrict__ bb, int writeScaled,
    int finalOut, const unsigned short* __restrict__ s1,
    const float* __restrict__ ue, const float* __restrict__ ie,
    float* __restrict__ outp) {
    int lane = threadIdx.x & 63;
    int lanelo = lane & 15;
    int quad = lane >> 4;
    int wid = (blockIdx.x * blockDim.x + threadIdx.x) >> 6;
    if (wid >= NTILES) return;

    // B-fragments from pre-converted bf16 W (vector loads, no conversion)
    short8 bWg[4][2], bWb[4][2];
#pragma unroll
    for (int t = 0; t < 4; ++t) {
#pragma unroll
        for (int h = 0; h < 2; ++h) {
            int n = t * 16 + lanelo;
            int k0 = h * 32 + quad * 8;
            bWg[t][h] = *(const short8*)&wgb[n * 64 + k0];
            bWb[t][h] = *(const short8*)&wbb[n * 64 + k0];
        }
    }
    float bgv[4], bbv[4];
#pragma unroll
    for (int t = 0; t < 4; ++t) {
        bgv[t] = bg[t * 16 + lanelo];
        bbv[t] = bb[t * 16 + lanelo];
    }

    int rbase = wid * 16;
    int arow = rbase + lanelo;
    short8 aG[2], aAG[2];
#pragma unroll
    for (int h = 0; h < 2; ++h) {
        uint4 ug = *(const uint4*)(gbuf + arow * 32 + h * 16 + quad * 4);
        uint4 ua = *(const uint4*)((const unsigned*)a_prev + arow * 32 + h * 16 + quad * 4);
        aG[h] = *(const short8*)&ug;
        uint4 up;
        up.x = pack_bf2(bf_lo(ua.x) * bf_lo(ug.x), bf_hi(ua.x) * bf_hi(ug.x));
        up.y = pack_bf2(bf_lo(ua.y) * bf_lo(ug.y), bf_hi(ua.y) * bf_hi(ug.y));
        up.z = pack_bf2(bf_lo(ua.z) * bf_lo(ug.z), bf_hi(ua.z) * bf_hi(ug.z));
        up.w = pack_bf2(bf_lo(ua.w) * bf_lo(ug.w), bf_hi(ua.w) * bf_hi(ug.w));
        aAG[h] = *(const short8*)&up;
    }
    floatx4 accg[4], accb[4];
#pragma unroll
    for (int t = 0; t < 4; ++t) {
        accg[t] = (floatx4)(0.f);
        accb[t] = (floatx4)(0.f);
    }
#pragma unroll
    for (int t = 0; t < 4; ++t) {
#pragma unroll
        for (int h = 0; h < 2; ++h) {
            accg[t] = __builtin_amdgcn_mfma_f32_16x16x32_bf16(aG[h], bWg[t][h], accg[t], 0, 0, 0);
            accb[t] = __builtin_amdgcn_mfma_f32_16x16x32_bf16(aAG[h], bWb[t][h], accb[t], 0, 0, 0);
        }
    }
    // epilogue in C/D layout: row = rbase + quad*4 + i, col = t*16 + lanelo
    float nv[4][4];
    float ss[4] = {0.f, 0.f, 0.f, 0.f};
#pragma unroll
    for (int i = 0; i < 4; ++i) {
        int r = rbase + quad * 4 + i;
#pragma unroll
        for (int t = 0; t < 4; ++t) {
            float a = __uint_as_float((unsigned)a_prev[r * 64 + t * 16 + lanelo] << 16);
            float e1 = accg[t][i] + bgv[t] + a;
            e1 = e1 >= 0.f ? e1 : 0.2f * e1;
            float e2 = accb[t][i] + bbv[t];
            e2 = e2 >= 0.f ? e2 : 0.2f * e2;
            float v = e1 + e2;
            nv[i][t] = v;
            ss[i] += v * v;
        }
    }
#pragma unroll
    for (int m = 1; m < 16; m <<= 1) {
#pragma unroll
        for (int i = 0; i < 4; ++i) ss[i] += __shfl_xor(ss[i], m, 64);
    }
#pragma unroll
    for (int i = 0; i < 4; ++i) {
        int r = rbase + quad * 4 + i;
        float rn = 1.0f / fmaxf(sqrtf(ss[i]), 1e-12f);
        float sc = isq[r] * rn;
        if (finalOut) {
#pragma unroll
            for (int t = 0; t < 4; ++t) {
                int idx = r * 64 + t * 16 + lanelo;
                float rr = nv[i][t] * rn;
                float s1v = __uint_as_float((unsigned)s1[idx] << 16);
                float s2v = __uint_as_float((unsigned)a_prev[idx] << 16);
                float ev = (r < NU) ? ue[idx] : ie[idx - NU * 64];
                outp[idx] = 0.25f * (ev + s1v + s2v + rr);
            }
        } else {
#pragma unroll
            for (int t = 0; t < 4; ++t) {
                int idx = r * 64 + t * 16 + lanelo;
                float rr = nv[i][t] * rn;
                snap_l[idx] = f2bf(rr);
                if (writeScaled)
                    ((unsigned short*)gbuf)[idx] = f2bf(nv[i][t] * sc);
            }
        }
    }
}

// ---------------- launch ----------------

extern "C" void kernel_launch(void* const* d_in, const int* in_sizes, int n_in,
                              void* d_out, int out_size, void* d_ws, size_t ws_size,
                              hipStream_t stream) {
    const float* u_emb = (const float*)d_in[0];
    const float* i_emb = (const float*)d_in[1];
    const float* Wgc = (const float*)d_in[2];
    const float* bgc = (const float*)d_in[3];
    const float* Wbi = (const float*)d_in[4];
    const float* bbi = (const float*)d_in[5];
    const int* edge_u = (const int*)d_in[6];
    const int* edge_i = (const int*)d_in[7];
    float* out = (float*)d_out;

    char* w = (char*)d_ws;
    auto alloc = [&](size_t bytes) {
        char* p = w;
        w += (bytes + 255) & ~(size_t)255;
        return p;
    };
    const size_t ROWBYTES = (size_t)(NTOT + 1) * EDIM * 2;   // +1 sentinel row
    int* deg = (int*)alloc((size_t)NTOT * 4);
    int* start = (int*)alloc((size_t)NTOT * 4);
    unsigned* bcur = (unsigned*)alloc((size_t)NBKT * NSHARD * BCUR_STRIDE * 4);  // 128 KB
    int* bktbase = (int*)alloc(256 * 4);
    int* csr = (int*)alloc((size_t)2 * NE * 4);
    float* isq = (float*)alloc((size_t)NTOT * 4);
    float* inv = (float*)alloc((size_t)NTOT * 4);
    unsigned short* wgb = (unsigned short*)alloc((size_t)NLAYERS * 4096 * 2);
    unsigned short* wbb = (unsigned short*)alloc((size_t)NLAYERS * 4096 * 2);
    unsigned* snap0 = (unsigned*)alloc((size_t)NTOT * EDIM * 2);
    unsigned* snap1 = (unsigned*)alloc((size_t)NTOT * EDIM * 2);
    unsigned* snap2 = (unsigned*)alloc((size_t)NTOT * EDIM * 2);
    unsigned* Ebuf = (unsigned*)alloc(ROWBYTES);
    unsigned* gbuf = (unsigned*)alloc(ROWBYTES);    // = embS (in-place)
    // pair bins (29.4 MB) alias snap1+snap2 (38.4 MB contiguous): bins are dead
    // before dense l=0 writes snap1.
    uint2* bbuf = (uint2*)snap1;

    // graph prep: bin pairs -> bucket prefix -> per-bucket CSR build
    hipMemsetAsync(bcur, 0, (size_t)NBKT * NSHARD * BCUR_STRIDE * 4, stream);
    k_binpairs<<<BIN_NBLK, 256, 0, stream>>>(edge_u, edge_i, bcur, bbuf);
    k_bktprefix<<<1, 256, 0, stream>>>(bcur, bktbase);
    k_buildcsr<<<NBKT, 1024, 0, stream>>>(bbuf, bcur, bktbase, deg, start, isq, inv, csr);
    k_init<<<(NTOT * EDIM / 4 + 255) / 256, 256, 0, stream>>>(
        u_emb, i_emb, isq, snap0, gbuf, Wgc, Wbi, wgb, wbb, Ebuf);

    const int gatherBlocks = (NPAIR * 64 + 255) / 256;  // one wave per 2 rows
    const int denseBlocks = (NTILES * 64 + 255) / 256;  // one wave per 16-row tile
    const unsigned short* aprev[3] = {(unsigned short*)snap0, (unsigned short*)snap1,
                                      (unsigned short*)snap2};
    unsigned short* snaps[3] = {(unsigned short*)snap1, (unsigned short*)snap2,
                                (unsigned short*)snap1 /*unused for l=2*/};
    for (int l = 0; l < NLAYERS; ++l) {
        // E[n] = inv[n] * sum embS[m]      (embS = isq*emb, pre-scaled)
        k_gather<<<gatherBlocks, 256, 0, stream>>>(gbuf, Ebuf, csr, start, deg, inv);
        // g[n] = isq[n] * sum E[m]
        k_gather<<<gatherBlocks, 256, 0, stream>>>(Ebuf, gbuf, csr, start, deg, isq);
        k_dense_mfma<<<denseBlocks, 256, 0, stream>>>(
            aprev[l], gbuf, snaps[l], isq, wgb + (size_t)l * 4096, wbb + (size_t)l * 4096,
            bgc + (size_t)l * 64, bbi + (size_t)l * 64,
            l < NLAYERS - 1 ? 1 : 0,              // writeScaled
            l == NLAYERS - 1 ? 1 : 0,             // finalOut (fused k_out)
            (const unsigned short*)snap1, u_emb, i_emb, out);
    }
}

// Round 9
// 468.413 us; speedup vs baseline: 1.1564x; 1.1441x over previous
//
#include <hip/hip_runtime.h>
#include <cstdint>
#include <cstddef>

#define NU 100000
#define NI 50000
#define NTOT 150000
#define EDIM 64
#define NE 1000000
#define NLAYERS 3
#define NTILES (NTOT / 16)                            // 9375
#define NPAIR (NTOT / 2)                              // 75000 (gather: 2 rows/wave)

// ---- binned CSR build (two-level: LDS stage -> contiguous global chunks) ----
#define NBKT 256
#define NPB 586                    // nodes per bucket (256*586 = 150016 >= NTOT)
#define NSHARD 1
#define BCAP 13312                 // packed pairs per bucket; max expected ~12.1K
#define BCUR_STRIDE 16             // u32s -> 64B per cursor line
#define BIN_EPB 1024               // edges per binpairs block
#define BIN_NBLK ((NE + BIN_EPB - 1) / BIN_EPB)       // 977
#define LCAP 28                    // LDS pairs per bucket (mean 8, v-mean 12)
#define LPAD 29                    // +1 pad -> stride 29 u32s, conflict-free flush
#define SLICE_CAP 13312            // ints; max bucket pair-count ~12.1K

typedef __attribute__((ext_vector_type(8))) short short8;   // 8 bf16 (4 VGPRs)
typedef __attribute__((ext_vector_type(4))) float floatx4;  // 4 fp32 acc

// ---------------- bf16 helpers (raw-bit, RNE) ----------------
__device__ inline unsigned short f2bf(float f) {
    unsigned u = __float_as_uint(f);
    u += 0x7fffu + ((u >> 16) & 1u);
    return (unsigned short)(u >> 16);
}
__device__ inline unsigned pack_bf2(float a, float b) {
    unsigned ua = __float_as_uint(a); ua += 0x7fffu + ((ua >> 16) & 1u);
    unsigned ub = __float_as_uint(b); ub += 0x7fffu + ((ub >> 16) & 1u);
    return (ua >> 16) | (ub & 0xffff0000u);
}
__device__ inline float bf_lo(unsigned u) { return __uint_as_float(u << 16); }
__device__ inline float bf_hi(unsigned u) { return __uint_as_float(u & 0xffff0000u); }

// ---------------- phase A: two-level binning of packed (local,other) ----------------
// Pair word = (node - bucket*NPB) << 18 | other   (other < 150000 < 2^18,
// local < 586 < 2^10). Each block bins 2048 endpoint-pairs into 256 LDS
// buckets, then flushes each bucket as ONE contiguous global chunk (single
// cursor atomicAdd per bucket per block). Line-neighbors in bbuf are written
// within the same block's flush window -> lines merge in L2 before eviction.
// (Rounds 4-8: any scheme whose line-neighbors arrived at distant times paid
// ~85-95us / ~82-95MB writeback; this is the fix.)
__global__ __launch_bounds__(256) void k_binpairs(const int* __restrict__ eu,
                                                  const int* __restrict__ ei,
                                                  unsigned* __restrict__ bcur,
                                                  unsigned* __restrict__ bbuf) {
    __shared__ unsigned lbuf[NBKT * LPAD];   // 29.7 KB
    __shared__ int lcnt[NBKT];
    int t = threadIdx.x;
    if (t < NBKT) lcnt[t] = 0;
    __syncthreads();
    int ebase = blockIdx.x * BIN_EPB + t;
#pragma unroll
    for (int k = 0; k < 4; ++k) {
        int e = ebase + k * 256;
        if (e < NE) {
            int u = eu[e];
            int v = NU + ei[e];
            int b0 = u / NPB;
            int w0 = ((u - b0 * NPB) << 18) | v;
            int p0 = atomicAdd(&lcnt[b0], 1);
            if (p0 < LCAP) lbuf[b0 * LPAD + p0] = (unsigned)w0;
            else {
                unsigned gp = atomicAdd(&bcur[b0 * BCUR_STRIDE], 1u);
                if (gp < BCAP) bbuf[(size_t)b0 * BCAP + gp] = (unsigned)w0;
            }
            int b1 = v / NPB;
            int w1 = ((v - b1 * NPB) << 18) | u;
            int p1 = atomicAdd(&lcnt[b1], 1);
            if (p1 < LCAP) lbuf[b1 * LPAD + p1] = (unsigned)w1;
            else {
                unsigned gp = atomicAdd(&bcur[b1 * BCUR_STRIDE], 1u);
                if (gp < BCAP) bbuf[(size_t)b1 * BCAP + gp] = (unsigned)w1;
            }
        }
    }
    __syncthreads();
    // flush: thread t owns bucket t; one reservation, sequential chunk write
    int nb = min(lcnt[t], LCAP);
    if (nb > 0) {
        unsigned gp = atomicAdd(&bcur[t * BCUR_STRIDE], (unsigned)nb);
        for (int i = 0; i < nb; ++i) {
            unsigned idx = gp + i;
            if (idx < BCAP) bbuf[(size_t)t * BCAP + idx] = lbuf[t * LPAD + i];
        }
    }
}

// ---------------- bucket-total exclusive prefix (1 block) ----------------
__global__ void k_bktprefix(const unsigned* __restrict__ bcur, int* __restrict__ bktbase) {
    __shared__ int sm[256];
    int t = threadIdx.x;   // t = bucket
    int tot = (int)bcur[t * BCUR_STRIDE];
    if (tot > BCAP) tot = BCAP;
    sm[t] = tot;
    __syncthreads();
    for (int off = 1; off < 256; off <<= 1) {
        int tmp = (t >= off) ? sm[t - off] : 0;
        __syncthreads();
        sm[t] += tmp;
        __syncthreads();
    }
    bktbase[t] = sm[t] - tot;   // exclusive
}

// ---------------- phase B: per-bucket degree/scan/CSR build, coalesced flush ----
// One block per bucket. deg/start/isq/inv identical to the old pipeline by
// construction (buckets are contiguous node ranges). CSR slice assembled in
// LDS, flushed fully coalesced.
__global__ __launch_bounds__(1024) void k_buildcsr(
    const unsigned* __restrict__ bbuf, const unsigned* __restrict__ bcur,
    const int* __restrict__ bktbase, int* __restrict__ deg, int* __restrict__ start,
    float* __restrict__ isq, float* __restrict__ inv, int* __restrict__ csr) {
    __shared__ int slice[SLICE_CAP];   // scan temp (first 1024), then csr slice
    __shared__ int lcur[NPB];          // per-node count, then placement cursor
    __shared__ int scnt_s;
    int b = blockIdx.x;
    int t = threadIdx.x;
    int n0 = b * NPB;
    int nn = NTOT - n0;
    if (nn > NPB) nn = NPB;
    if (nn < 0) nn = 0;
    if (t < NPB) lcur[t] = 0;
    if (t == 0) {
        int c = (int)bcur[b * BCUR_STRIDE];
        scnt_s = c < BCAP ? c : BCAP;
    }
    __syncthreads();
    int c = scnt_s;
    const unsigned* pb = bbuf + (size_t)b * BCAP;
    // count pass
    for (int i = t; i < c; i += 1024) atomicAdd(&lcur[(int)(pb[i] >> 18)], 1);
    __syncthreads();
    // exclusive scan over nn counts (1024-wide Hillis-Steele in slice[])
    int cnt_t = (t < nn) ? lcur[t] : 0;
    slice[t] = cnt_t;
    __syncthreads();
    for (int off = 1; off < 1024; off <<= 1) {
        int tmp = (t >= off) ? slice[t - off] : 0;
        __syncthreads();
        slice[t] += tmp;
        __syncthreads();
    }
    int excl = slice[t] - cnt_t;
    int slen = slice[1023];            // total pairs in bucket
    int bb = bktbase[b];
    if (t < nn) {
        int n = n0 + t;
        deg[n] = cnt_t;
        start[n] = bb + excl;
        float df = (float)cnt_t;
        isq[n] = cnt_t > 0 ? 1.0f / sqrtf(df) : 0.f;
        inv[n] = cnt_t > 0 ? 1.0f / df : 0.f;
    }
    __syncthreads();                   // everyone done reading slice & lcur
    if (t < nn) lcur[t] = excl;        // reuse as placement cursor
    __syncthreads();
    // place pass
    for (int i = t; i < c; i += 1024) {
        unsigned pr = pb[i];
        int idx = atomicAdd(&lcur[(int)(pr >> 18)], 1);
        if (idx < SLICE_CAP) slice[idx] = (int)(pr & 0x3FFFFu);
    }
    __syncthreads();
    if (slen > SLICE_CAP) slen = SLICE_CAP;
    for (int i = t; i < slen; i += 1024) csr[bb + i] = slice[i];
}

// init (fused): snap0 = bf16(concat(u,i)); embS = bf16(isq*emb) into gbuf;
// + W f32->bf16 pre-conversion (first 3072 threads);
// + zero the sentinel row NTOT of Ebuf and gbuf (first 16 threads).
__global__ void k_init(const float* __restrict__ ue, const float* __restrict__ ie,
                       const float* __restrict__ isq,
                       unsigned* __restrict__ snap0, unsigned* gbuf,
                       const float* __restrict__ Wg, const float* __restrict__ Wb,
                       unsigned short* __restrict__ wgb, unsigned short* __restrict__ wbb,
                       unsigned* __restrict__ Ebuf) {
    int i = blockIdx.x * blockDim.x + threadIdx.x;
    const int n4 = NTOT * EDIM / 4;
    const int nw4 = NLAYERS * 4096 / 4;   // 3072
    if (i < nw4) {
        float4 g4 = ((const float4*)Wg)[i];
        float4 b4 = ((const float4*)Wb)[i];
        uint2 g, b;
        g.x = pack_bf2(g4.x, g4.y); g.y = pack_bf2(g4.z, g4.w);
        b.x = pack_bf2(b4.x, b4.y); b.y = pack_bf2(b4.z, b4.w);
        ((uint2*)wgb)[i] = g;
        ((uint2*)wbb)[i] = b;
    }
    if (i < 16) {
        ((uint2*)(Ebuf + NTOT * 32))[i] = make_uint2(0u, 0u);
        ((uint2*)(gbuf + NTOT * 32))[i] = make_uint2(0u, 0u);
    }
    if (i < n4) {
        const int nu4 = NU * EDIM / 4;
        float4 v = (i < nu4) ? ((const float4*)ue)[i] : ((const float4*)ie)[i - nu4];
        float s = isq[i >> 4];
        uint2 b, bs;
        b.x = pack_bf2(v.x, v.y);
        b.y = pack_bf2(v.z, v.w);
        bs.x = pack_bf2(v.x * s, v.y * s);
        bs.y = pack_bf2(v.z * s, v.w * s);
        ((uint2*)snap0)[i] = b;
        ((uint2*)gbuf)[i] = bs;
    }
}

// ---------------- sparse gather (pull), bf16 rows, unweighted ----------------
// v4: TWO rows per wave — lanes 0-31 own row 2gw, lanes 32-63 own row 2gw+1.
// Each half broadcasts its own neighbor list via per-lane-src shfl; every lane
// accumulates ALL neighbors of its row (dword l2), so no cross-lane reduce.
// 16 independent loads in flight per wave. Out-of-range slots read the zero
// sentinel row at index NTOT.
__global__ __launch_bounds__(256) void k_gather(
    const unsigned* __restrict__ in_bf, unsigned* __restrict__ out_bf,
    const int* __restrict__ csr, const int* __restrict__ start,
    const int* __restrict__ deg, const float* __restrict__ sA) {
    int gw = (blockIdx.x * 256 + threadIdx.x) >> 6;   // wave id = row pair
    int lane = threadIdx.x & 63;
    if (gw >= NPAIR) return;
    int l2 = lane & 31;
    int hbase = lane & 32;                 // 0 or 32: this half's lane base
    int row = gw * 2 + (lane >> 5);
    int s0 = start[row];
    int dg = deg[row];
    int dgo = __shfl_xor(dg, 32);          // other half's degree
    int dgmax = max(dg, dgo);              // uniform across the wave
    float acc0 = 0.f, acc1 = 0.f;
    for (int j0 = 0; j0 < dgmax; j0 += 32) {
        int nidx = NTOT;                   // sentinel zero row
        if (j0 + l2 < dg) nidx = csr[s0 + j0 + l2];
        int jlim = min(32, dgmax - j0);
        for (int j = 0; j < jlim; j += 16) {
            int mm[16];
            unsigned uu[16];
#pragma unroll
            for (int k = 0; k < 16; ++k)
                mm[k] = __shfl(nidx, hbase + j + k);
#pragma unroll
            for (int k = 0; k < 16; ++k)
                uu[k] = in_bf[mm[k] * 32 + l2];
#pragma unroll
            for (int k = 0; k < 16; ++k) {
                acc0 += bf_lo(uu[k]);
                acc1 += bf_hi(uu[k]);
            }
        }
    }
    float s = sA[row];
    out_bf[row * 32 + l2] = pack_bf2(s * acc0, s * acc1);
}

// ---------------- dense per-row update via MFMA (all-bf16 state) ----------------
// One wave per 16-row tile. Reads g rows (from gbuf) + a rows (snap_prev).
// writeScaled: also write embS = isq*emb bf16 IN PLACE over gbuf (per-tile
// local; tiles disjoint across waves). finalOut: instead of writing snap_l,
// fuse the output mean: out = 0.25*(emb_f32 + snap1 + a_prev + rr) where
// rr is this layer's (unrounded) normalized embedding. gbuf intentionally
// NOT __restrict__.
__global__ __launch_bounds__(256) void k_dense_mfma(
    const unsigned short* __restrict__ a_prev, unsigned* gbuf,
    unsigned short* __restrict__ snap_l, const float* __restrict__ isq,
    const unsigned short* __restrict__ wgb, const unsigned short* __restrict__ wbb,
    const float* __restrict__ bg, const float* __restrict__ bb, int writeScaled,
    int finalOut, const unsigned short* __restrict__ s1,
    const float* __restrict__ ue, const float* __restrict__ ie,
    float* __restrict__ outp) {
    int lane = threadIdx.x & 63;
    int lanelo = lane & 15;
    int quad = lane >> 4;
    int wid = (blockIdx.x * blockDim.x + threadIdx.x) >> 6;
    if (wid >= NTILES) return;

    // B-fragments from pre-converted bf16 W (vector loads, no conversion)
    short8 bWg[4][2], bWb[4][2];
#pragma unroll
    for (int t = 0; t < 4; ++t) {
#pragma unroll
        for (int h = 0; h < 2; ++h) {
            int n = t * 16 + lanelo;
            int k0 = h * 32 + quad * 8;
            bWg[t][h] = *(const short8*)&wgb[n * 64 + k0];
            bWb[t][h] = *(const short8*)&wbb[n * 64 + k0];
        }
    }
    float bgv[4], bbv[4];
#pragma unroll
    for (int t = 0; t < 4; ++t) {
        bgv[t] = bg[t * 16 + lanelo];
        bbv[t] = bb[t * 16 + lanelo];
    }

    int rbase = wid * 16;
    int arow = rbase + lanelo;
    short8 aG[2], aAG[2];
#pragma unroll
    for (int h = 0; h < 2; ++h) {
        uint4 ug = *(const uint4*)(gbuf + arow * 32 + h * 16 + quad * 4);
        uint4 ua = *(const uint4*)((const unsigned*)a_prev + arow * 32 + h * 16 + quad * 4);
        aG[h] = *(const short8*)&ug;
        uint4 up;
        up.x = pack_bf2(bf_lo(ua.x) * bf_lo(ug.x), bf_hi(ua.x) * bf_hi(ug.x));
        up.y = pack_bf2(bf_lo(ua.y) * bf_lo(ug.y), bf_hi(ua.y) * bf_hi(ug.y));
        up.z = pack_bf2(bf_lo(ua.z) * bf_lo(ug.z), bf_hi(ua.z) * bf_hi(ug.z));
        up.w = pack_bf2(bf_lo(ua.w) * bf_lo(ug.w), bf_hi(ua.w) * bf_hi(ug.w));
        aAG[h] = *(const short8*)&up;
    }
    floatx4 accg[4], accb[4];
#pragma unroll
    for (int t = 0; t < 4; ++t) {
        accg[t] = (floatx4)(0.f);
        accb[t] = (floatx4)(0.f);
    }
#pragma unroll
    for (int t = 0; t < 4; ++t) {
#pragma unroll
        for (int h = 0; h < 2; ++h) {
            accg[t] = __builtin_amdgcn_mfma_f32_16x16x32_bf16(aG[h], bWg[t][h], accg[t], 0, 0, 0);
            accb[t] = __builtin_amdgcn_mfma_f32_16x16x32_bf16(aAG[h], bWb[t][h], accb[t], 0, 0, 0);
        }
    }
    // epilogue in C/D layout: row = rbase + quad*4 + i, col = t*16 + lanelo
    float nv[4][4];
    float ss[4] = {0.f, 0.f, 0.f, 0.f};
#pragma unroll
    for (int i = 0; i < 4; ++i) {
        int r = rbase + quad * 4 + i;
#pragma unroll
        for (int t = 0; t < 4; ++t) {
            float a = __uint_as_float((unsigned)a_prev[r * 64 + t * 16 + lanelo] << 16);
            float e1 = accg[t][i] + bgv[t] + a;
            e1 = e1 >= 0.f ? e1 : 0.2f * e1;
            float e2 = accb[t][i] + bbv[t];
            e2 = e2 >= 0.f ? e2 : 0.2f * e2;
            float v = e1 + e2;
            nv[i][t] = v;
            ss[i] += v * v;
        }
    }
#pragma unroll
    for (int m = 1; m < 16; m <<= 1) {
#pragma unroll
        for (int i = 0; i < 4; ++i) ss[i] += __shfl_xor(ss[i], m, 64);
    }
#pragma unroll
    for (int i = 0; i < 4; ++i) {
        int r = rbase + quad * 4 + i;
        float rn = 1.0f / fmaxf(sqrtf(ss[i]), 1e-12f);
        float sc = isq[r] * rn;
        if (finalOut) {
#pragma unroll
            for (int t = 0; t < 4; ++t) {
                int idx = r * 64 + t * 16 + lanelo;
                float rr = nv[i][t] * rn;
                float s1v = __uint_as_float((unsigned)s1[idx] << 16);
                float s2v = __uint_as_float((unsigned)a_prev[idx] << 16);
                float ev = (r < NU) ? ue[idx] : ie[idx - NU * 64];
                outp[idx] = 0.25f * (ev + s1v + s2v + rr);
            }
        } else {
#pragma unroll
            for (int t = 0; t < 4; ++t) {
                int idx = r * 64 + t * 16 + lanelo;
                float rr = nv[i][t] * rn;
                snap_l[idx] = f2bf(rr);
                if (writeScaled)
                    ((unsigned short*)gbuf)[idx] = f2bf(nv[i][t] * sc);
            }
        }
    }
}

// ---------------- launch ----------------

extern "C" void kernel_launch(void* const* d_in, const int* in_sizes, int n_in,
                              void* d_out, int out_size, void* d_ws, size_t ws_size,
                              hipStream_t stream) {
    const float* u_emb = (const float*)d_in[0];
    const float* i_emb = (const float*)d_in[1];
    const float* Wgc = (const float*)d_in[2];
    const float* bgc = (const float*)d_in[3];
    const float* Wbi = (const float*)d_in[4];
    const float* bbi = (const float*)d_in[5];
    const int* edge_u = (const int*)d_in[6];
    const int* edge_i = (const int*)d_in[7];
    float* out = (float*)d_out;

    char* w = (char*)d_ws;
    auto alloc = [&](size_t bytes) {
        char* p = w;
        w += (bytes + 255) & ~(size_t)255;
        return p;
    };
    const size_t ROWBYTES = (size_t)(NTOT + 1) * EDIM * 2;   // +1 sentinel row
    int* deg = (int*)alloc((size_t)NTOT * 4);
    int* start = (int*)alloc((size_t)NTOT * 4);
    unsigned* bcur = (unsigned*)alloc((size_t)NBKT * BCUR_STRIDE * 4);  // 16 KB
    int* bktbase = (int*)alloc(256 * 4);
    int* csr = (int*)alloc((size_t)2 * NE * 4);
    float* isq = (float*)alloc((size_t)NTOT * 4);
    float* inv = (float*)alloc((size_t)NTOT * 4);
    unsigned short* wgb = (unsigned short*)alloc((size_t)NLAYERS * 4096 * 2);
    unsigned short* wbb = (unsigned short*)alloc((size_t)NLAYERS * 4096 * 2);
    unsigned* snap0 = (unsigned*)alloc((size_t)NTOT * EDIM * 2);
    unsigned* snap1 = (unsigned*)alloc((size_t)NTOT * EDIM * 2);
    unsigned* snap2 = (unsigned*)alloc((size_t)NTOT * EDIM * 2);
    unsigned* Ebuf = (unsigned*)alloc(ROWBYTES);
    unsigned* gbuf = (unsigned*)alloc(ROWBYTES);    // = embS (in-place)
    // packed pair bins (13.7 MB) alias snap1 (19.2 MB): bins are dead before
    // dense l=0 writes snap1.
    unsigned* bbuf = (unsigned*)snap1;

    // graph prep: two-level bin -> bucket prefix -> per-bucket CSR build
    hipMemsetAsync(bcur, 0, (size_t)NBKT * BCUR_STRIDE * 4, stream);
    k_binpairs<<<BIN_NBLK, 256, 0, stream>>>(edge_u, edge_i, bcur, bbuf);
    k_bktprefix<<<1, 256, 0, stream>>>(bcur, bktbase);
    k_buildcsr<<<NBKT, 1024, 0, stream>>>(bbuf, bcur, bktbase, deg, start, isq, inv, csr);
    k_init<<<(NTOT * EDIM / 4 + 255) / 256, 256, 0, stream>>>(
        u_emb, i_emb, isq, snap0, gbuf, Wgc, Wbi, wgb, wbb, Ebuf);

    const int gatherBlocks = (NPAIR * 64 + 255) / 256;  // one wave per 2 rows
    const int denseBlocks = (NTILES * 64 + 255) / 256;  // one wave per 16-row tile
    const unsigned short* aprev[3] = {(unsigned short*)snap0, (unsigned short*)snap1,
                                      (unsigned short*)snap2};
    unsigned short* snaps[3] = {(unsigned short*)snap1, (unsigned short*)snap2,
                                (unsigned short*)snap1 /*unused for l=2*/};
    for (int l = 0; l < NLAYERS; ++l) {
        // E[n] = inv[n] * sum embS[m]      (embS = isq*emb, pre-scaled)
        k_gather<<<gatherBlocks, 256, 0, stream>>>(gbuf, Ebuf, csr, start, deg, inv);
        // g[n] = isq[n] * sum E[m]
        k_gather<<<gatherBlocks, 256, 0, stream>>>(Ebuf, gbuf, csr, start, deg, isq);
        k_dense_mfma<<<denseBlocks, 256, 0, stream>>>(
            aprev[l], gbuf, snaps[l], isq, wgb + (size_t)l * 4096, wbb + (size_t)l * 4096,
            bgc + (size_t)l * 64, bbi + (size_t)l * 64,
            l < NLAYERS - 1 ? 1 : 0,              // writeScaled
            l == NLAYERS - 1 ? 1 : 0,             // finalOut (fused k_out)
            (const unsigned short*)snap1, u_emb, i_emb, out);
    }
}